// Round 1
// baseline (1597.664 us; speedup 1.0000x reference)
//
#include <hip/hip_runtime.h>
#include <cstddef>

// Problem constants (MultiHeadKvtAttention): B=8, N=1024, DIM=768, H=12, D=64, TOPK=100
#define DIMC 768
#define HEADS 12
#define HEAD_DIM 64
#define TOPK 100
#define SCALE 0.125f
#define BATCH 8
#define SEQ 1024
#define RB 8       // rows per attention block
#define CAP 256    // compacted-index capacity per row (fallback loop if exceeded)

__device__ __forceinline__ unsigned mkey(float f) {
  // monotonic float->uint transform: a > b  <=>  mkey(a) > mkey(b)
  unsigned u = __float_as_uint(f);
  return u ^ ((unsigned)((int)u >> 31) | 0x80000000u);
}

// ---------------------------------------------------------------------------
// fp32 GEMM: C[M,N] = A[M,K] @ W[K,N] (+ bias). 128x128 tile, K-step 16,
// 256 threads, 8x8 micro-tile per thread. All dims are exact multiples here
// (M=8192, K=768, N in {2304, 768}) so no bounds checks.
// ---------------------------------------------------------------------------
template <bool BIAS>
__global__ __launch_bounds__(256) void gemm_f32(
    const float* __restrict__ A, const float* __restrict__ W,
    const float* __restrict__ bias, float* __restrict__ C,
    int M, int K, int N) {
  __shared__ float Al[16][128];  // A tile, transposed: Al[k][m]
  __shared__ float Bl[16][128];  // W tile: Bl[k][n]
  const int t = threadIdx.x;
  const int row0 = blockIdx.y * 128, col0 = blockIdx.x * 128;
  const int tx = t & 15, ty = t >> 4;

  // staging maps (two float4 loads per thread per tile for each operand)
  const int a_r = t >> 2, a_c = (t & 3) * 4;     // A: 128 rows x 16 cols
  const int b_r = t >> 5, b_c = (t & 31) * 4;    // W: 16 rows x 128 cols
  const float* Ap0 = A + (size_t)(row0 + a_r) * K + a_c;
  const float* Ap1 = A + (size_t)(row0 + a_r + 64) * K + a_c;
  const float* Wp0 = W + (size_t)b_r * N + col0 + b_c;
  const float* Wp1 = W + (size_t)(b_r + 8) * N + col0 + b_c;

  float acc[8][8];
#pragma unroll
  for (int i = 0; i < 8; ++i)
#pragma unroll
    for (int j = 0; j < 8; ++j) acc[i][j] = 0.f;

  for (int k0 = 0; k0 < K; k0 += 16) {
    float4 a0 = *(const float4*)(Ap0 + k0);
    float4 a1 = *(const float4*)(Ap1 + k0);
    float4 w0 = *(const float4*)(Wp0 + (size_t)k0 * N);
    float4 w1 = *(const float4*)(Wp1 + (size_t)k0 * N);
    Al[a_c + 0][a_r] = a0.x; Al[a_c + 1][a_r] = a0.y;
    Al[a_c + 2][a_r] = a0.z; Al[a_c + 3][a_r] = a0.w;
    Al[a_c + 0][a_r + 64] = a1.x; Al[a_c + 1][a_r + 64] = a1.y;
    Al[a_c + 2][a_r + 64] = a1.z; Al[a_c + 3][a_r + 64] = a1.w;
    *(float4*)&Bl[b_r][b_c] = w0;
    *(float4*)&Bl[b_r + 8][b_c] = w1;
    __syncthreads();
#pragma unroll
    for (int kk = 0; kk < 16; ++kk) {
      float av[8], bv[8];
      *(float4*)&av[0] = *(const float4*)&Al[kk][ty * 8];
      *(float4*)&av[4] = *(const float4*)&Al[kk][ty * 8 + 4];
      *(float4*)&bv[0] = *(const float4*)&Bl[kk][tx * 8];
      *(float4*)&bv[4] = *(const float4*)&Bl[kk][tx * 8 + 4];
#pragma unroll
      for (int i = 0; i < 8; ++i)
#pragma unroll
        for (int j = 0; j < 8; ++j) acc[i][j] = fmaf(av[i], bv[j], acc[i][j]);
    }
    __syncthreads();
  }

#pragma unroll
  for (int i = 0; i < 8; ++i) {
    float* Cp = C + (size_t)(row0 + ty * 8 + i) * N + col0 + tx * 8;
    float4 o0 = make_float4(acc[i][0], acc[i][1], acc[i][2], acc[i][3]);
    float4 o1 = make_float4(acc[i][4], acc[i][5], acc[i][6], acc[i][7]);
    if (BIAS) {
      const float* bp = bias + col0 + tx * 8;
      o0.x += bp[0]; o0.y += bp[1]; o0.z += bp[2]; o0.w += bp[3];
      o1.x += bp[4]; o1.y += bp[5]; o1.z += bp[6]; o1.w += bp[7];
    }
    *(float4*)Cp = o0;
    *(float4*)(Cp + 4) = o1;
  }
}

// ---------------------------------------------------------------------------
// Fused attention with exact top-k mask.
// Grid: (SEQ/RB, BATCH*HEADS). Block: 256 threads.
// qkv layout: [B, N, 3, H, D] flat (GEMM output columns = which*768 + h*64 + d)
// Output: aout[B, N, H*D] (= [B,N,768]) ready for the proj GEMM.
// ---------------------------------------------------------------------------
__global__ __launch_bounds__(256) void attn_topk(
    const float* __restrict__ qkv, float* __restrict__ aout) {
  __shared__ float s[RB][SEQ];            // 32 KB: scores -> probabilities
  __shared__ float qs[RB][HEAD_DIM];      // 2 KB: scaled q rows
  __shared__ unsigned hist[RB][256];      // 8 KB: radix histograms
  __shared__ unsigned short idxl[RB][CAP];// 4 KB: compacted kept indices
  __shared__ unsigned selp[RB];           // selected key prefix per row
  __shared__ int selw[RB];                // remaining rank within prefix
  __shared__ unsigned rcnt[RB];
  __shared__ float rinv[RB];

  const int t = threadIdx.x;
  const int n0 = blockIdx.x * RB;
  const int bh = blockIdx.y;
  const int b = bh / HEADS, h = bh - b * HEADS;
  const float* base = qkv + (size_t)b * SEQ * (3 * DIMC) + h * HEAD_DIM;

  // ---- load q rows (scaled) ----
  for (int i = t; i < RB * HEAD_DIM; i += 256) {
    int r = i >> 6, d = i & 63;
    qs[r][d] = base[(size_t)(n0 + r) * (3 * DIMC) + d] * SCALE;
  }
  if (t < RB) { selp[t] = 0u; selw[t] = TOPK; rcnt[t] = 0u; }
  __syncthreads();

  // ---- scores: thread owns columns m = t + mi*256 for all RB rows ----
  {
    const float* kb = base + DIMC;
    float acc[4][RB];
#pragma unroll
    for (int mi = 0; mi < 4; ++mi)
#pragma unroll
      for (int r = 0; r < RB; ++r) acc[mi][r] = 0.f;
    for (int d0 = 0; d0 < HEAD_DIM; d0 += 4) {
      float4 k4[4];
#pragma unroll
      for (int mi = 0; mi < 4; ++mi)
        k4[mi] = *(const float4*)(kb + (size_t)(t + mi * 256) * (3 * DIMC) + d0);
#pragma unroll
      for (int r = 0; r < RB; ++r) {
        float4 q4 = *(const float4*)&qs[r][d0];
#pragma unroll
        for (int mi = 0; mi < 4; ++mi)
          acc[mi][r] += k4[mi].x * q4.x + k4[mi].y * q4.y +
                        k4[mi].z * q4.z + k4[mi].w * q4.w;
      }
    }
#pragma unroll
    for (int mi = 0; mi < 4; ++mi)
#pragma unroll
      for (int r = 0; r < RB; ++r) s[r][t + mi * 256] = acc[mi][r];
  }
  __syncthreads();

  // ---- exact k-th largest per row via 4-pass radix select (32 thr/row) ----
  const int row = t >> 5, l = t & 31;
  for (int pass = 0; pass < 4; ++pass) {
    const int shift = 24 - pass * 8;
    for (int i = l; i < 256; i += 32) hist[row][i] = 0u;
    __syncthreads();
    const unsigned pref = selp[row];
    const int want = selw[row];
    for (int i = l; i < SEQ; i += 32) {
      unsigned key = mkey(s[row][i]);
      bool cand = (pass == 0) || (((key ^ pref) >> (shift + 8)) == 0u);
      if (cand) atomicAdd(&hist[row][(key >> shift) & 255u], 1u);
    }
    __syncthreads();
    // descending scan: lane l covers bins [255-8l .. 248-8l]
    unsigned local = 0;
#pragma unroll
    for (int j = 0; j < 8; ++j) local += hist[row][255 - 8 * l - j];
    unsigned incl = local;
    for (int off = 1; off < 32; off <<= 1) {
      unsigned u = __shfl_up(incl, off, 32);
      if (l >= off) incl += u;
    }
    const unsigned above = incl - local;
    if ((int)above < want && (int)incl >= want) {  // unique lane
      unsigned run = above;
#pragma unroll
      for (int j = 0; j < 8; ++j) {
        int bin = 255 - 8 * l - j;
        unsigned c = hist[row][bin];
        if (run + c >= (unsigned)want) {
          selp[row] = pref | ((unsigned)bin << shift);
          selw[row] = want - (int)run;
          break;
        }
        run += c;
      }
    }
    __syncthreads();
  }

  // ---- softmax over kept entries + index compaction ----
  {
    const unsigned thr = selp[row];  // exact key of k-th largest
    float mx = -1e30f;
    for (int i = l; i < SEQ; i += 32) mx = fmaxf(mx, s[row][i]);
#pragma unroll
    for (int off = 16; off > 0; off >>= 1) mx = fmaxf(mx, __shfl_xor(mx, off, 32));
    float sum = 0.f;
    for (int i = l; i < SEQ; i += 32) {
      float v = s[row][i];
      float p = 0.f;
      if (mkey(v) >= thr) {  // matches reference `attn >= kth` (ties kept)
        p = expf(v - mx);
        unsigned pos = atomicAdd(&rcnt[row], 1u);
        if (pos < CAP) idxl[row][pos] = (unsigned short)i;
      }
      s[row][i] = p;
      sum += p;
    }
#pragma unroll
    for (int off = 16; off > 0; off >>= 1) sum += __shfl_xor(sum, off, 32);
    if (l == 0) rinv[row] = 1.f / sum;
  }
  __syncthreads();

  // ---- PV: sparse accumulation over ~TOPK kept columns ----
  const float* vb = base + 2 * DIMC;
#pragma unroll
  for (int it = 0; it < 2; ++it) {
    const int r = it * 4 + (t >> 6);
    const int d = t & 63;
    const unsigned cnt = rcnt[r];
    const float inv = rinv[r];
    float o = 0.f;
    if (cnt <= CAP) {
      for (unsigned j = 0; j < cnt; ++j) {
        int m = idxl[r][j];
        o = fmaf(s[r][m], vb[(size_t)m * (3 * DIMC) + d], o);
      }
    } else {  // tie-overflow fallback (vanishingly rare with continuous data)
      for (int m = 0; m < SEQ; ++m) {
        float p = s[r][m];
        if (p != 0.f) o = fmaf(p, vb[(size_t)m * (3 * DIMC) + d], o);
      }
    }
    aout[((size_t)b * SEQ + n0 + r) * DIMC + h * HEAD_DIM + d] = o * inv;
  }
}

// ---------------------------------------------------------------------------
extern "C" void kernel_launch(void* const* d_in, const int* in_sizes, int n_in,
                              void* d_out, int out_size, void* d_ws, size_t ws_size,
                              hipStream_t stream) {
  (void)in_sizes; (void)n_in; (void)out_size; (void)ws_size;
  const float* x      = (const float*)d_in[0];  // [8,1024,768]
  const float* w_qkv  = (const float*)d_in[1];  // [768,2304]
  const float* w_proj = (const float*)d_in[2];  // [768,768]
  const float* b_proj = (const float*)d_in[3];  // [768]
  float* out = (float*)d_out;                   // [8,1024,768]

  const int M = BATCH * SEQ;                    // 8192
  float* qkv  = (float*)d_ws;                   // [8192, 2304]  (75.5 MB)
  float* aatt = qkv + (size_t)M * (3 * DIMC);   // [8192, 768]   (25.2 MB)

  // 1) QKV projection
  dim3 g1((3 * DIMC) / 128, M / 128);
  gemm_f32<false><<<g1, dim3(256), 0, stream>>>(x, w_qkv, nullptr, qkv,
                                                M, DIMC, 3 * DIMC);
  // 2) fused top-k attention
  dim3 g2(SEQ / RB, BATCH * HEADS);
  attn_topk<<<g2, dim3(256), 0, stream>>>(qkv, aatt);
  // 3) output projection + bias
  dim3 g3(DIMC / 128, M / 128);
  gemm_f32<true><<<g3, dim3(256), 0, stream>>>(aatt, w_proj, b_proj, out,
                                               M, DIMC, DIMC);
}